// Round 16
// baseline (121.990 us; speedup 1.0000x reference)
//
#include <hip/hip_runtime.h>

typedef unsigned short u16;
typedef unsigned int   u32;

typedef __bf16 bf16x8 __attribute__((ext_vector_type(8)));
typedef float  f32x4  __attribute__((ext_vector_type(4)));

#define B_DIM 4
#define T_DIM 8192
#define D_DIM 512
#define M_DIM (B_DIM * T_DIM)   // 32768
#define K_DIM D_DIM             // 512
#define NC    256               // chunks along T
#define LCH   32                // chunk length (NC*LCH == T_DIM)

__device__ __forceinline__ u16 f2bf(float f) {
  u32 u = __float_as_uint(f);
  u32 r = (u + 0x7FFFu + ((u >> 16) & 1u)) >> 16;   // RNE
  return (u16)r;
}
__device__ __forceinline__ float bf2f(u16 b) {
  return __uint_as_float(((u32)b) << 16);
}

// async global->LDS, 16B per lane; lds dest is wave-uniform base + lane*16
__device__ __forceinline__ void gload_lds16(const u16* g, u16* lds) {
  __builtin_amdgcn_global_load_lds(
      (const __attribute__((address_space(1))) void*)g,
      (__attribute__((address_space(3))) void*)lds, 16, 0, 0);
}

// ------------- fused conversion kernel (x -> bf16, W -> W^T bf16) -------------

__global__ __launch_bounds__(256) void convert_xw(const float4* __restrict__ x4,
                                                  u16* __restrict__ xb,
                                                  const float* __restrict__ W,
                                                  u16* __restrict__ wt, int n4) {
  const int bid = blockIdx.x;
  if (bid < 2048) {
    int i = bid * 256 + threadIdx.x;
    const int stride = 2048 * 256;
    for (; i < n4; i += stride) {
      float4 f = x4[i];
      u32 w0 = (u32)f2bf(f.x) | ((u32)f2bf(f.y) << 16);
      u32 w1 = (u32)f2bf(f.z) | ((u32)f2bf(f.w) << 16);
      *reinterpret_cast<uint2*>(xb + (size_t)i * 4) = make_uint2(w0, w1);
    }
  } else {
    int idx = (bid - 2048) * 256 + threadIdx.x;   // 0..65535
    int n  = idx & 1023;
    int k0 = (idx >> 10) * 8;
    float f[8];
#pragma unroll
    for (int j = 0; j < 8; ++j) f[j] = W[(size_t)(k0 + j) * 1024 + n];
    u32 w[4];
#pragma unroll
    for (int j = 0; j < 4; ++j)
      w[j] = (u32)f2bf(f[2 * j]) | ((u32)f2bf(f[2 * j + 1]) << 16);
    *reinterpret_cast<uint4*>(wt + (size_t)n * 512 + k0) = make_uint4(w[0], w[1], w[2], w[3]);
  }
}

// ---- GEMM: 256Mx128N, 8 waves 64x64, BK=64, 4-phase/K-tile (m201-style) ----
// 3 rolling bufs (A 32KB + B 16KB each; 144KB LDS, 1 block/CU).  Per K-tile t:
//   s_waitcnt vmcnt(6) [tile t's 6 loads done; t+1's 6 in flight] -> s_barrier
//   ph0 {bfr@kk0 x4 + af m0,m1@kk0; stage A0,A1(t+2); BAR; lgkm0+schedbar;
//        prio1; 8 MFMA (m0,m1 x n0..3); prio0; BAR}
//   ph1 {af m2,m3@kk0; stage A2,A3(t+2); ... 8 MFMA}
//   ph2 {bfr@kk1 x4 + af m0,m1@kk1; stage B0,B1(t+2); ... 8 MFMA}
//   ph3 {af m2,m3@kk1; ... 8 MFMA}
// vmcnt never drained to 0 until the tail (T4).  Stage t+2 writes buf
// (t+2)%3, last read in tile t-1 -> ordered by tile-t start barrier.
// LDS rows are 64 bf16 (128B) = 8 x 16B slots; slot_phys = slot_log^(row&7)
// (2-way on read = free), staged via inverse-swizzled GLOBAL source (rule 21).
// B rows j (call c: j=c*64+arow), p=j>>5: gn = (p&1)*512 + d0 + (p>>1)*32 +
// (j&31) -> hidden=acc[m][n], gate=acc[m][n+2] (n<2), ch = d0+32*wc+16n+l15.

#define BK 64
#define NTL 8

__global__ __launch_bounds__(512, 2) void gemm_act(const u16* __restrict__ xb,
                                                   const u16* __restrict__ wt,
                                                   u32* __restrict__ av_buf,
                                                   float* __restrict__ Asum,
                                                   float* __restrict__ Bsum) {
  __shared__ u16 As[3][16384];   // 3 x 32 KB (256 rows x 64 k)
  __shared__ u16 Bs[3][8192];    // 3 x 16 KB (128 rows x 64 k)

  const int tid  = threadIdx.x;
  const int lane = tid & 63;
  const int wave = tid >> 6;        // 0..7
  const int l15  = lane & 15;
  const int lh   = lane >> 4;       // 0..3
  const int wr   = wave >> 1;       // 0..3
  const int wc   = wave & 1;        // 0..1
  const int m_base = blockIdx.x * 256;
  const int d0     = blockIdx.y * 64;

  // staging: thread tid writes linear 16B slot tid of an 8KB (64-row) region
  const int arow = tid >> 3;                        // 0..63 row within region
  const int acol = (((tid & 7) ^ (arow & 7)) << 3); // inverse-swizzled k elems
  const int ldsw = wave * 512;                      // wave's 1KB within region
  int gnc[2];
#pragma unroll
  for (int c = 0; c < 2; ++c) {
    int j = c * 64 + arow;
    int p = j >> 5;
    gnc[c] = ((p & 1) ? 512 : 0) + d0 + ((p >> 1) << 5) + (j & 31);
  }

  f32x4 acc[4][4];
#pragma unroll
  for (int m = 0; m < 4; ++m)
#pragma unroll
    for (int n = 0; n < 4; ++n)
      acc[m][n] = (f32x4){0.f, 0.f, 0.f, 0.f};

#define SA(buf, kt, c)                                                      \
  gload_lds16(xb + (size_t)(m_base + (c) * 64 + arow) * K_DIM + (kt) * BK + acol, \
              &As[buf][(c) * 4096 + ldsw])
#define SB(buf, kt, c)                                                      \
  gload_lds16(wt + (size_t)gnc[c] * K_DIM + (kt) * BK + acol,               \
              &Bs[buf][(c) * 4096 + ldsw])

  // swizzled read offset (elems) for logical (row, 16B-slot = kk*4+lh)
#define AOFF(row, kk) ((row) * 64 + (((((kk) << 2) | lh) ^ ((row) & 7)) << 3))

#define WAITV(N) asm volatile("s_waitcnt vmcnt(" #N ")" ::: "memory")
#define LGKM0()                                                             \
  do {                                                                      \
    asm volatile("s_waitcnt lgkmcnt(0)" ::: "memory");                      \
    __builtin_amdgcn_sched_barrier(0);                                      \
  } while (0)
#define BAR() asm volatile("s_barrier" ::: "memory")

#define CLUSTER(mlo, kk)                                                    \
  do {                                                                      \
    __builtin_amdgcn_s_setprio(1);                                          \
    _Pragma("unroll")                                                       \
    for (int n = 0; n < 4; ++n)                                             \
      acc[mlo][n] = __builtin_amdgcn_mfma_f32_16x16x32_bf16(af0, bfr[n], acc[mlo][n], 0, 0, 0); \
    _Pragma("unroll")                                                       \
    for (int n = 0; n < 4; ++n)                                             \
      acc[mlo + 1][n] = __builtin_amdgcn_mfma_f32_16x16x32_bf16(af1, bfr[n], acc[mlo + 1][n], 0, 0, 0); \
    __builtin_amdgcn_s_setprio(0);                                          \
  } while (0)

#define TILE(cur, s2, kt2, DO)                                              \
  do {                                                                      \
    bf16x8 af0, af1, bfr[4];                                                \
    /* ---- ph0: kk0, m0/m1 ---- */                                         \
    _Pragma("unroll")                                                       \
    for (int n = 0; n < 4; ++n)                                             \
      bfr[n] = *reinterpret_cast<const bf16x8*>(&Bs[cur][AOFF(64 * wc + 16 * n + l15, 0)]); \
    af0 = *reinterpret_cast<const bf16x8*>(&As[cur][AOFF(64 * wr + l15, 0)]);      \
    af1 = *reinterpret_cast<const bf16x8*>(&As[cur][AOFF(64 * wr + 16 + l15, 0)]); \
    if (DO) { SA(s2, kt2, 0); SA(s2, kt2, 1); }                             \
    BAR(); LGKM0();                                                         \
    CLUSTER(0, 0);                                                          \
    BAR();                                                                  \
    /* ---- ph1: kk0, m2/m3 ---- */                                         \
    af0 = *reinterpret_cast<const bf16x8*>(&As[cur][AOFF(64 * wr + 32 + l15, 0)]); \
    af1 = *reinterpret_cast<const bf16x8*>(&As[cur][AOFF(64 * wr + 48 + l15, 0)]); \
    if (DO) { SA(s2, kt2, 2); SA(s2, kt2, 3); }                             \
    BAR(); LGKM0();                                                         \
    CLUSTER(2, 0);                                                          \
    BAR();                                                                  \
    /* ---- ph2: kk1, m0/m1 ---- */                                         \
    _Pragma("unroll")                                                       \
    for (int n = 0; n < 4; ++n)                                             \
      bfr[n] = *reinterpret_cast<const bf16x8*>(&Bs[cur][AOFF(64 * wc + 16 * n + l15, 1)]); \
    af0 = *reinterpret_cast<const bf16x8*>(&As[cur][AOFF(64 * wr + l15, 1)]);      \
    af1 = *reinterpret_cast<const bf16x8*>(&As[cur][AOFF(64 * wr + 16 + l15, 1)]); \
    if (DO) { SB(s2, kt2, 0); SB(s2, kt2, 1); }                             \
    BAR(); LGKM0();                                                         \
    CLUSTER(0, 1);                                                          \
    BAR();                                                                  \
    /* ---- ph3: kk1, m2/m3 ---- */                                         \
    af0 = *reinterpret_cast<const bf16x8*>(&As[cur][AOFF(64 * wr + 32 + l15, 1)]); \
    af1 = *reinterpret_cast<const bf16x8*>(&As[cur][AOFF(64 * wr + 48 + l15, 1)]); \
    BAR(); LGKM0();                                                         \
    CLUSTER(2, 1);                                                          \
    BAR();                                                                  \
  } while (0)

  // prologue: stage tiles 0 and 1 (6 loads each, tile-0's issued first)
  SA(0, 0, 0); SA(0, 0, 1); SA(0, 0, 2); SA(0, 0, 3); SB(0, 0, 0); SB(0, 0, 1);
  SA(1, 1, 0); SA(1, 1, 1); SA(1, 1, 2); SA(1, 1, 3); SB(1, 1, 0); SB(1, 1, 1);

#pragma unroll
  for (int t = 0; t < 6; ++t) {
    WAITV(6);                      // tile t's 6 loads done; t+1's in flight
    BAR();
    TILE(t % 3, (t + 2) % 3, t + 2, true);
  }
  WAITV(6); BAR(); TILE(0, 0, 0, false);   // t=6 (tile 7's loads in flight)
  WAITV(0); BAR(); TILE(1, 0, 0, false);   // t=7
#undef TILE
#undef CLUSTER
#undef SA
#undef SB
#undef WAITV
#undef LGKM0
#undef BAR

  // ---- epilogue: a = sigmoid(-gate), v = sigmoid(gate)*g(hidden); av packed;
  // ---- fused scan pass1: per 32-row chunk, (A,B) = chunk-composed affine map.
  const int row_w = m_base + 64 * wr;
#pragma unroll
  for (int h = 0; h < 2; ++h) {          // chunk half: rows [32h, 32h+32) of wave
    float Ar[2][2], Br[2][2];            // [n][mm]
#pragma unroll
    for (int mm = 0; mm < 2; ++mm) {
      const int m = 2 * h + mm;
#pragma unroll
      for (int n = 0; n < 2; ++n) {
        float A = 1.f, Bv = 0.f;
        const int dch = d0 + 32 * wc + 16 * n + l15;
#pragma unroll
        for (int r = 0; r < 4; ++r) {
          float hid = acc[m][n][r];
          float gt  = acc[m][n + 2][r];
          float e   = __expf(gt);
          float inv = 1.f / (1.f + e);         // a = sigmoid(-gate)
          float g   = (hid >= 0.f) ? (hid + 0.5f) : (1.f / (1.f + __expf(-hid)));
          float v   = (e * inv) * g;           // z * g
          u16 abf = f2bf(inv);
          u16 vbf = f2bf(v);
          const int grow = row_w + 16 * m + 4 * lh + r;
          av_buf[(size_t)grow * D_DIM + dch] = (u32)abf | ((u32)vbf << 16);
          float afv = bf2f(abf), vfv = bf2f(vbf);
          Bv = afv * Bv + vfv;
          A *= afv;
        }
        Ar[n][mm] = A; Br[n][mm] = Bv;
      }
    }
    // inclusive scan across lh (4 segments of 4 rows each), per (n, mm)
#pragma unroll
    for (int n = 0; n < 2; ++n)
#pragma unroll
      for (int mm = 0; mm < 2; ++mm) {
        float A = Ar[n][mm], Bv = Br[n][mm];
#pragma unroll
        for (int d = 1; d <= 2; d <<= 1) {
          float pA = __shfl(A, lane - 16 * d);
          float pB = __shfl(Bv, lane - 16 * d);
          if (lh >= d) { Bv = A * pB + Bv; A = A * pA; }
        }
        Ar[n][mm] = A; Br[n][mm] = Bv;
      }
    if (lh == 3) {   // lanes 48..63 hold full 16-row segment results
      const int grow = row_w + 32 * h;
      const int b = grow >> 13;           // / 8192
      const int c = (grow & 8191) >> 5;   // / 32
      const size_t o = ((size_t)(b * NC + c)) * D_DIM;
#pragma unroll
      for (int n = 0; n < 2; ++n) {
        const int dch = d0 + 32 * wc + 16 * n + l15;
        float Ac = Ar[n][0] * Ar[n][1];
        float Bc = Ar[n][1] * Br[n][0] + Br[n][1];
        Asum[o + dch] = Ac;
        Bsum[o + dch] = Bc;
      }
    }
  }
}

// ------- chunk-level scan: one wave per (b,d) channel, shfl affine scan -------

__global__ __launch_bounds__(256) void scan_pass2(const float* __restrict__ Asum,
                                                  const float* __restrict__ Bsum,
                                                  float* __restrict__ carry) {
  const int w    = (blockIdx.x << 2) + (threadIdx.x >> 6);  // 0..2047
  const int lane = threadIdx.x & 63;
  const int b = w >> 9;
  const int d = w & 511;
  const size_t base = ((size_t)(b * NC + lane * 4)) * D_DIM + d;
  float A[4], Bv[4];
#pragma unroll
  for (int i = 0; i < 4; ++i) {
    A[i]  = Asum[base + (size_t)i * D_DIM];
    Bv[i] = Bsum[base + (size_t)i * D_DIM];
  }
  float La = 1.f, Lb = 0.f;
#pragma unroll
  for (int i = 0; i < 4; ++i) { Lb = A[i] * Lb + Bv[i]; La *= A[i]; }
  float Sa = La, Sb = Lb;
#pragma unroll
  for (int dlt = 1; dlt < 64; dlt <<= 1) {
    float pa = __shfl_up(Sa, dlt, 64);
    float pb = __shfl_up(Sb, dlt, 64);
    if (lane >= dlt) { Sb = Sa * pb + Sb; Sa = Sa * pa; }
  }
  float Eb = __shfl_up(Sb, 1, 64);
  float h = (lane == 0) ? 0.f : Eb;
#pragma unroll
  for (int i = 0; i < 4; ++i) {
    carry[base + (size_t)i * D_DIM] = h;
    h = A[i] * h + Bv[i];
  }
}

// ---------------- final within-chunk scan + output (d2, 16 waves/CU) ---------

__global__ __launch_bounds__(256) void scan_pass3(const u32* __restrict__ av_buf,
                                                  const float2* __restrict__ carry,
                                                  float2* __restrict__ out) {
  const int c  = blockIdx.x;
  const int b  = blockIdx.y;
  const int d2 = threadIdx.x;       // 0..255 (channel pair)
  float2 hh = carry[((size_t)(b * NC + c)) * 256 + d2];
  float h0 = hh.x, h1 = hh.y;
  const size_t rowbase = (size_t)b * T_DIM + (size_t)c * LCH;
  for (int t = 0; t < LCH; ++t) {
    const size_t idx = (rowbase + t) * 256 + d2;
    uint2 w = reinterpret_cast<const uint2*>(av_buf)[idx];
    h0 = bf2f(w.x & 0xffff) * h0 + bf2f(w.x >> 16);
    h1 = bf2f(w.y & 0xffff) * h1 + bf2f(w.y >> 16);
    out[idx] = make_float2(h0, h1);
  }
}

// ---------------- launch ----------------

extern "C" void kernel_launch(void* const* d_in, const int* in_sizes, int n_in,
                              void* d_out, int out_size, void* d_ws, size_t ws_size,
                              hipStream_t stream) {
  const float* x = (const float*)d_in[0];   // [4,8192,512]
  const float* W = (const float*)d_in[1];   // [512,1024]
  float* out = (float*)d_out;               // [4,8192,512]

  char* ws = (char*)d_ws;
  u16*   xb     = (u16*)(ws + 0);             // 33,554,432
  u16*   wtp    = (u16*)(ws + 33554432);      //  1,048,576
  u32*   av_buf = (u32*)(ws + 34603008);      // 67,108,864 (a lo16 | v hi16)
  float* Asum   = (float*)(ws + 101711872);   //  2,097,152
  float* Bsum   = (float*)(ws + 103809024);   //  2,097,152
  float* carry  = (float*)(ws + 105906176);   //  2,097,152  (end 108,003,328)
  if (ws_size < 108003328ULL) return;

  convert_xw<<<2304, 256, 0, stream>>>((const float4*)x, xb, W, wtp, (M_DIM * K_DIM) / 4);
  gemm_act<<<dim3(M_DIM / 256, D_DIM / 64), 512, 0, stream>>>(xb, wtp, av_buf, Asum, Bsum);
  scan_pass2<<<512, 256, 0, stream>>>(Asum, Bsum, carry);
  scan_pass3<<<dim3(NC, B_DIM), 256, 0, stream>>>(av_buf, (const float2*)carry, (float2*)out);
}

// Round 17
// 113.742 us; speedup vs baseline: 1.0725x; 1.0725x over previous
//
#include <hip/hip_runtime.h>

typedef unsigned short u16;
typedef unsigned int   u32;

typedef __bf16 bf16x8 __attribute__((ext_vector_type(8)));
typedef float  f32x4  __attribute__((ext_vector_type(4)));

#define B_DIM 4
#define T_DIM 8192
#define D_DIM 512
#define M_DIM (B_DIM * T_DIM)   // 32768
#define K_DIM D_DIM             // 512
#define NC    256               // chunks along T
#define LCH   32                // chunk length (NC*LCH == T_DIM)

__device__ __forceinline__ u16 f2bf(float f) {
  u32 u = __float_as_uint(f);
  u32 r = (u + 0x7FFFu + ((u >> 16) & 1u)) >> 16;   // RNE
  return (u16)r;
}
__device__ __forceinline__ float bf2f(u16 b) {
  return __uint_as_float(((u32)b) << 16);
}

// async global->LDS, 16B per lane; lds dest is wave-uniform base + lane*16
__device__ __forceinline__ void gload_lds16(const u16* g, u16* lds) {
  __builtin_amdgcn_global_load_lds(
      (const __attribute__((address_space(1))) void*)g,
      (__attribute__((address_space(3))) void*)lds, 16, 0, 0);
}

// ------------- fused conversion kernel (x -> bf16, W -> W^T bf16) -------------

__global__ __launch_bounds__(256) void convert_xw(const float4* __restrict__ x4,
                                                  u16* __restrict__ xb,
                                                  const float* __restrict__ W,
                                                  u16* __restrict__ wt, int n4) {
  const int bid = blockIdx.x;
  if (bid < 2048) {
    int i = bid * 256 + threadIdx.x;
    const int stride = 2048 * 256;
    for (; i < n4; i += stride) {
      float4 f = x4[i];
      u32 w0 = (u32)f2bf(f.x) | ((u32)f2bf(f.y) << 16);
      u32 w1 = (u32)f2bf(f.z) | ((u32)f2bf(f.w) << 16);
      *reinterpret_cast<uint2*>(xb + (size_t)i * 4) = make_uint2(w0, w1);
    }
  } else {
    int idx = (bid - 2048) * 256 + threadIdx.x;   // 0..65535
    int n  = idx & 1023;
    int k0 = (idx >> 10) * 8;
    float f[8];
#pragma unroll
    for (int j = 0; j < 8; ++j) f[j] = W[(size_t)(k0 + j) * 1024 + n];
    u32 w[4];
#pragma unroll
    for (int j = 0; j < 4; ++j)
      w[j] = (u32)f2bf(f[2 * j]) | ((u32)f2bf(f[2 * j + 1]) << 16);
    *reinterpret_cast<uint4*>(wt + (size_t)n * 512 + k0) = make_uint4(w[0], w[1], w[2], w[3]);
  }
}

// ---- GEMM: 256Mx256N, 8 waves (2wr x 4wc), wave 128x64 (acc[8][4]), BK=32 ----
// LDS-port roofline fix: wave 128x64 cuts LDS B/FLOP 0.042 -> 0.031; 2 bufs
// (A 16KB + B 16KB each = 64KB total) keep 2 blocks/CU.  Counted-vmcnt 1-ahead
// schedule (T4 - never drain in loop):
//   iter t: s_barrier [all waves done computing buf (t+1)&1 at iter t-1] ->
//           STAGE(t+1 -> buf (t+1)&1) -> s_waitcnt vmcnt(4) [stage t done;
//           stage t+1 in flight ACROSS the barrier] -> COMPUTE(buf t&1).
// Swizzle: slot_phys = slot_log^(pair&7) via inverse-swizzled GLOBAL source
// (rule #21; proven 0 conflicts).  Staging: 4 calls x 8KB (A rows 0-127,
// 128-255; B rows 0-127, 128-255).
// B rows j, p=j>>5: gn = (p&1)*512 + d0 + (p>>1)*32 + (j&31) ->
// hidden=acc[m][n] (n<2), gate=acc[m][n+2], ch = d0 + 32*wc + 16n + l15,
// d0 = blockIdx.y*128, wc in 0..3.

#define BK 32
#define NT 16

__global__ __launch_bounds__(512, 2) void gemm_act(const u16* __restrict__ xb,
                                                   const u16* __restrict__ wt,
                                                   u32* __restrict__ av_buf,
                                                   float* __restrict__ Asum,
                                                   float* __restrict__ Bsum) {
  __shared__ u16 As[2][8192];   // 2 x 16 KB (256 rows x 32 k)
  __shared__ u16 Bs[2][8192];   // 2 x 16 KB (256 rows x 32 k)

  const int tid  = threadIdx.x;
  const int lane = tid & 63;
  const int wave = tid >> 6;        // 0..7
  const int l15  = lane & 15;
  const int lh   = lane >> 4;       // 0..3
  const int wr   = wave >> 2;       // 0..1  (row half: 128 rows)
  const int wc   = wave & 3;        // 0..3  (col quarter: 64 cols)
  const int m_base = blockIdx.x * 256;
  const int d0     = blockIdx.y * 128;

  // staging: thread tid -> linear 16B slot tid within a 128-row (8KB) region
  const int pairl = tid >> 3;                   // 0..63
  const int slog  = (tid & 7) ^ (pairl & 7);    // logical slot
  const int lrow  = (pairl << 1) | (slog >> 2); // 0..127
  const int scol  = (slog & 3) << 3;            // k elem offset 0/8/16/24
  const int garow0 = m_base + lrow;             // A call 0
  const int garow1 = garow0 + 128;              // A call 1
  int gnB[2];
#pragma unroll
  for (int c = 0; c < 2; ++c) {
    int j = c * 128 + lrow;
    int p = j >> 5;
    gnB[c] = ((p & 1) ? 512 : 0) + d0 + ((p >> 1) << 5) + (j & 31);
  }
  const int ldsw = wave * 512;                  // wave's 1KB within a call

  f32x4 acc[8][4];
#pragma unroll
  for (int m = 0; m < 8; ++m)
#pragma unroll
    for (int n = 0; n < 4; ++n)
      acc[m][n] = (f32x4){0.f, 0.f, 0.f, 0.f};

#define STAGE(buf, kt)                                                      \
  do {                                                                      \
    const int ko = (kt) * BK + scol;                                        \
    gload_lds16(xb + (size_t)garow0 * K_DIM + ko, &As[buf][ldsw]);          \
    gload_lds16(xb + (size_t)garow1 * K_DIM + ko, &As[buf][4096 + ldsw]);   \
    gload_lds16(wt + (size_t)gnB[0] * K_DIM + ko, &Bs[buf][ldsw]);          \
    gload_lds16(wt + (size_t)gnB[1] * K_DIM + ko, &Bs[buf][4096 + ldsw]);   \
  } while (0)

  // swizzled read offset (elems) for logical (row, k-chunk lh)
#define AOFF(row) (((row) >> 1) * 64 + (((((((row) & 1) << 2) | lh)) ^ (((row) >> 1) & 7)) << 3))

#define COMPUTE(cur)                                                        \
  do {                                                                      \
    bf16x8 bfr[4];                                                          \
    _Pragma("unroll")                                                       \
    for (int n = 0; n < 4; ++n)                                             \
      bfr[n] = *reinterpret_cast<const bf16x8*>(&Bs[cur][AOFF(64 * wc + 16 * n + l15)]); \
    _Pragma("unroll")                                                       \
    for (int mh = 0; mh < 2; ++mh) {                                        \
      bf16x8 af[4];                                                         \
      _Pragma("unroll")                                                     \
      for (int mm = 0; mm < 4; ++mm)                                        \
        af[mm] = *reinterpret_cast<const bf16x8*>(&As[cur][AOFF(128 * wr + 64 * mh + 16 * mm + l15)]); \
      __builtin_amdgcn_s_setprio(1);                                        \
      _Pragma("unroll")                                                     \
      for (int mm = 0; mm < 4; ++mm)                                        \
        _Pragma("unroll")                                                   \
        for (int n = 0; n < 4; ++n)                                         \
          acc[4 * mh + mm][n] = __builtin_amdgcn_mfma_f32_16x16x32_bf16(af[mm], bfr[n], acc[4 * mh + mm][n], 0, 0, 0); \
      __builtin_amdgcn_s_setprio(0);                                        \
    }                                                                       \
  } while (0)

#define WAITV(N) asm volatile("s_waitcnt vmcnt(" #N ")" ::: "memory")
#define BAR()    asm volatile("s_barrier" ::: "memory")

  STAGE(0, 0);
#pragma unroll
  for (int t = 0; t < NT - 1; ++t) {
    BAR();                           // all waves done reading buf (t+1)&1
    STAGE((t + 1) & 1, t + 1);       // in flight across next barrier
    WAITV(4);                        // stage t done; stage t+1 outstanding
    COMPUTE(t & 1);
  }
  BAR();
  WAITV(0);                          // drain stage 15
  COMPUTE((NT - 1) & 1);
#undef STAGE
#undef COMPUTE
#undef WAITV
#undef BAR

  // ---- epilogue: a = sigmoid(-gate), v = sigmoid(gate)*g(hidden); av packed;
  // ---- fused scan pass1: per 32-row chunk, (A,B) = chunk-composed affine map.
  const int row_w = m_base + 128 * wr;
#pragma unroll
  for (int h = 0; h < 4; ++h) {          // chunk: rows [32h, 32h+32) of wave
    float Ar[2][2], Br[2][2];            // [n][mm]
#pragma unroll
    for (int mm = 0; mm < 2; ++mm) {
      const int m = 2 * h + mm;
#pragma unroll
      for (int n = 0; n < 2; ++n) {
        float A = 1.f, Bv = 0.f;
        const int dch = d0 + 32 * wc + 16 * n + l15;
#pragma unroll
        for (int r = 0; r < 4; ++r) {
          float hid = acc[m][n][r];
          float gt  = acc[m][n + 2][r];
          float e   = __expf(gt);
          float inv = 1.f / (1.f + e);         // a = sigmoid(-gate)
          float g   = (hid >= 0.f) ? (hid + 0.5f) : (1.f / (1.f + __expf(-hid)));
          float v   = (e * inv) * g;           // z * g
          u16 abf = f2bf(inv);
          u16 vbf = f2bf(v);
          const int grow = row_w + 16 * m + 4 * lh + r;
          av_buf[(size_t)grow * D_DIM + dch] = (u32)abf | ((u32)vbf << 16);
          float afv = bf2f(abf), vfv = bf2f(vbf);
          Bv = afv * Bv + vfv;
          A *= afv;
        }
        Ar[n][mm] = A; Br[n][mm] = Bv;
      }
    }
    // inclusive scan across lh (4 segments of 4 rows each), per (n, mm)
#pragma unroll
    for (int n = 0; n < 2; ++n)
#pragma unroll
      for (int mm = 0; mm < 2; ++mm) {
        float A = Ar[n][mm], Bv = Br[n][mm];
#pragma unroll
        for (int d = 1; d <= 2; d <<= 1) {
          float pA = __shfl(A, lane - 16 * d);
          float pB = __shfl(Bv, lane - 16 * d);
          if (lh >= d) { Bv = A * pB + Bv; A = A * pA; }
        }
        Ar[n][mm] = A; Br[n][mm] = Bv;
      }
    if (lh == 3) {   // lanes 48..63 hold full 16-row segment results
      const int grow = row_w + 32 * h;
      const int b = grow >> 13;           // / 8192
      const int c = (grow & 8191) >> 5;   // / 32
      const size_t o = ((size_t)(b * NC + c)) * D_DIM;
#pragma unroll
      for (int n = 0; n < 2; ++n) {
        const int dch = d0 + 32 * wc + 16 * n + l15;
        float Ac = Ar[n][0] * Ar[n][1];
        float Bc = Ar[n][1] * Br[n][0] + Br[n][1];
        Asum[o + dch] = Ac;
        Bsum[o + dch] = Bc;
      }
    }
  }
}

// ------- chunk-level scan: one wave per (b,d) channel, shfl affine scan -------

__global__ __launch_bounds__(256) void scan_pass2(const float* __restrict__ Asum,
                                                  const float* __restrict__ Bsum,
                                                  float* __restrict__ carry) {
  const int w    = (blockIdx.x << 2) + (threadIdx.x >> 6);  // 0..2047
  const int lane = threadIdx.x & 63;
  const int b = w >> 9;
  const int d = w & 511;
  const size_t base = ((size_t)(b * NC + lane * 4)) * D_DIM + d;
  float A[4], Bv[4];
#pragma unroll
  for (int i = 0; i < 4; ++i) {
    A[i]  = Asum[base + (size_t)i * D_DIM];
    Bv[i] = Bsum[base + (size_t)i * D_DIM];
  }
  float La = 1.f, Lb = 0.f;
#pragma unroll
  for (int i = 0; i < 4; ++i) { Lb = A[i] * Lb + Bv[i]; La *= A[i]; }
  float Sa = La, Sb = Lb;
#pragma unroll
  for (int dlt = 1; dlt < 64; dlt <<= 1) {
    float pa = __shfl_up(Sa, dlt, 64);
    float pb = __shfl_up(Sb, dlt, 64);
    if (lane >= dlt) { Sb = Sa * pb + Sb; Sa = Sa * pa; }
  }
  float Eb = __shfl_up(Sb, 1, 64);
  float h = (lane == 0) ? 0.f : Eb;
#pragma unroll
  for (int i = 0; i < 4; ++i) {
    carry[base + (size_t)i * D_DIM] = h;
    h = A[i] * h + Bv[i];
  }
}

// ---------------- final within-chunk scan + output (d2, 16 waves/CU) ---------

__global__ __launch_bounds__(256) void scan_pass3(const u32* __restrict__ av_buf,
                                                  const float2* __restrict__ carry,
                                                  float2* __restrict__ out) {
  const int c  = blockIdx.x;
  const int b  = blockIdx.y;
  const int d2 = threadIdx.x;       // 0..255 (channel pair)
  float2 hh = carry[((size_t)(b * NC + c)) * 256 + d2];
  float h0 = hh.x, h1 = hh.y;
  const size_t rowbase = (size_t)b * T_DIM + (size_t)c * LCH;
  for (int t = 0; t < LCH; ++t) {
    const size_t idx = (rowbase + t) * 256 + d2;
    uint2 w = reinterpret_cast<const uint2*>(av_buf)[idx];
    h0 = bf2f(w.x & 0xffff) * h0 + bf2f(w.x >> 16);
    h1 = bf2f(w.y & 0xffff) * h1 + bf2f(w.y >> 16);
    out[idx] = make_float2(h0, h1);
  }
}

// ---------------- launch ----------------

extern "C" void kernel_launch(void* const* d_in, const int* in_sizes, int n_in,
                              void* d_out, int out_size, void* d_ws, size_t ws_size,
                              hipStream_t stream) {
  const float* x = (const float*)d_in[0];   // [4,8192,512]
  const float* W = (const float*)d_in[1];   // [512,1024]
  float* out = (float*)d_out;               // [4,8192,512]

  char* ws = (char*)d_ws;
  u16*   xb     = (u16*)(ws + 0);             // 33,554,432
  u16*   wtp    = (u16*)(ws + 33554432);      //  1,048,576
  u32*   av_buf = (u32*)(ws + 34603008);      // 67,108,864 (a lo16 | v hi16)
  float* Asum   = (float*)(ws + 101711872);   //  2,097,152
  float* Bsum   = (float*)(ws + 103809024);   //  2,097,152
  float* carry  = (float*)(ws + 105906176);   //  2,097,152  (end 108,003,328)
  if (ws_size < 108003328ULL) return;

  convert_xw<<<2304, 256, 0, stream>>>((const float4*)x, xb, W, wtp, (M_DIM * K_DIM) / 4);
  gemm_act<<<dim3(M_DIM / 256, D_DIM / 128), 512, 0, stream>>>(xb, wtp, av_buf, Asum, Bsum);
  scan_pass2<<<512, 256, 0, stream>>>(Asum, Bsum, carry);
  scan_pass3<<<dim3(NC, B_DIM), 256, 0, stream>>>(av_buf, (const float2*)carry, (float2*)out);
}

// Round 18
// 109.425 us; speedup vs baseline: 1.1148x; 1.0395x over previous
//
#include <hip/hip_runtime.h>

typedef unsigned short u16;
typedef unsigned int   u32;

typedef __bf16 bf16x8 __attribute__((ext_vector_type(8)));
typedef float  f32x4  __attribute__((ext_vector_type(4)));

#define B_DIM 4
#define T_DIM 8192
#define D_DIM 512
#define M_DIM (B_DIM * T_DIM)   // 32768
#define K_DIM D_DIM             // 512
#define NC    256               // chunks along T
#define LCH   32                // chunk length (NC*LCH == T_DIM)

__device__ __forceinline__ u16 f2bf(float f) {
  u32 u = __float_as_uint(f);
  u32 r = (u + 0x7FFFu + ((u >> 16) & 1u)) >> 16;   // RNE
  return (u16)r;
}
__device__ __forceinline__ float bf2f(u16 b) {
  return __uint_as_float(((u32)b) << 16);
}

// async global->LDS, 16B per lane; lds dest is wave-uniform base + lane*16
__device__ __forceinline__ void gload_lds16(const u16* g, u16* lds) {
  __builtin_amdgcn_global_load_lds(
      (const __attribute__((address_space(1))) void*)g,
      (__attribute__((address_space(3))) void*)lds, 16, 0, 0);
}

// ------------- fused conversion kernel (x -> bf16, W -> W^T bf16) -------------

__global__ __launch_bounds__(256) void convert_xw(const float4* __restrict__ x4,
                                                  u16* __restrict__ xb,
                                                  const float* __restrict__ W,
                                                  u16* __restrict__ wt, int n4) {
  const int bid = blockIdx.x;
  if (bid < 2048) {
    int i = bid * 256 + threadIdx.x;
    const int stride = 2048 * 256;
    for (; i < n4; i += stride) {
      float4 f = x4[i];
      u32 w0 = (u32)f2bf(f.x) | ((u32)f2bf(f.y) << 16);
      u32 w1 = (u32)f2bf(f.z) | ((u32)f2bf(f.w) << 16);
      *reinterpret_cast<uint2*>(xb + (size_t)i * 4) = make_uint2(w0, w1);
    }
  } else {
    int idx = (bid - 2048) * 256 + threadIdx.x;   // 0..65535
    int n  = idx & 1023;
    int k0 = (idx >> 10) * 8;
    float f[8];
#pragma unroll
    for (int j = 0; j < 8; ++j) f[j] = W[(size_t)(k0 + j) * 1024 + n];
    u32 w[4];
#pragma unroll
    for (int j = 0; j < 4; ++j)
      w[j] = (u32)f2bf(f[2 * j]) | ((u32)f2bf(f[2 * j + 1]) << 16);
    *reinterpret_cast<uint4*>(wt + (size_t)n * 512 + k0) = make_uint4(w[0], w[1], w[2], w[3]);
  }
}

// ---- GEMM: 256Mx128N, 8 waves, BK=32, 3-buf rolling counted-vmcnt pipeline ----
// (round-9 exact — best measured 56.4us; r9 geometry is the read-minimum of
// the family: square 64x64 wave split minimizes LDS reads/step, and 64x64
// (64 VGPR + 64 acc) is the largest wave tile sustaining 4 waves/SIMD.)
// Wave (wr=wave>>1, wc=wave&1): rows 64*wr..+63, cols 64*wc..+63 -> acc[4][4].
// Pipeline: prologue stages tiles 0,1; iter t: s_waitcnt vmcnt(3) [tile t's 3
// loads done; tile t+1's 3 still in flight] -> s_barrier [all waves' t-loads
// done] -> STAGE(t+2) -> COMPUTE(t).  Never vmcnt(0) until the tail (T4).
// Stage t+2 writes buf (t+2)%3 consumed at iter t-1; this iter's barrier
// orders it.  NOTE: the wait MUST precede the barrier (own-loads-then-barrier
// = all-loads guarantee); BAR-then-wait-own is racy.
// LDS per buf: A 256x32 (16KB), B 128x32 (8KB); slot_phys = slot_log^(pair&7)
// swizzle staged via inverse-swizzled GLOBAL source (rule #21; 0 conflicts).
// B tile rows p=row>>5: gn = (p&1)*512 + d0 + (p>>1)*32 + (row&31) ->
// hidden=acc[m][n], gate=acc[m][n+2] (n<2), ch dch = d0+32*wc+16n+l15.

#define BK 32
#define NT 16

__global__ __launch_bounds__(512, 4) void gemm_act(const u16* __restrict__ xb,
                                                   const u16* __restrict__ wt,
                                                   u32* __restrict__ av_buf,
                                                   float* __restrict__ Asum,
                                                   float* __restrict__ Bsum) {
  __shared__ u16 As[3][8192];   // 3 x 16 KB (256 rows x 32 k)
  __shared__ u16 Bs[3][4096];   // 3 x 8 KB  (128 rows x 32 k)

  const int tid  = threadIdx.x;
  const int lane = tid & 63;
  const int wave = tid >> 6;        // 0..7
  const int l15  = lane & 15;
  const int lh   = lane >> 4;       // 0..3
  const int wr   = wave >> 1;       // 0..3
  const int wc   = wave & 1;        // 0..1
  const int m_base = blockIdx.x * 256;
  const int d0     = blockIdx.y * 64;

  // staging: slot s = tid (0..511); pair = s>>3, phys = s&7; logical source:
  const int pairl = tid >> 3;                  // 0..63 (pair within region)
  const int slog  = (tid & 7) ^ (pairl & 7);   // logical slot
  const int lrow  = (pairl << 1) | (slog >> 2); // 0..127
  const int scol  = (slog & 3) << 3;            // k elem offset 0/8/16/24
  const int garow0 = m_base + lrow;             // A call 0: rows 0..127
  const int garow1 = garow0 + 128;              // A call 1: rows 128..255
  const int pB = lrow >> 5;
  const int gn = ((pB & 1) ? 512 : 0) + d0 + ((pB >> 1) << 5) + (lrow & 31);
  const int ldsw = wave * 512;                  // wave's 1KB within a call

  f32x4 acc[4][4];
#pragma unroll
  for (int m = 0; m < 4; ++m)
#pragma unroll
    for (int n = 0; n < 4; ++n)
      acc[m][n] = (f32x4){0.f, 0.f, 0.f, 0.f};

#define STAGE(buf, kt)                                                      \
  do {                                                                      \
    const int ko = (kt) * BK + scol;                                        \
    gload_lds16(xb + (size_t)garow0 * K_DIM + ko, &As[buf][ldsw]);          \
    gload_lds16(xb + (size_t)garow1 * K_DIM + ko, &As[buf][4096 + ldsw]);   \
    gload_lds16(wt + (size_t)gn * K_DIM + ko, &Bs[buf][ldsw]);              \
  } while (0)

  // swizzled read offset (elems) for logical (row, k-chunk lh)
#define AOFF(row) (((row) >> 1) * 64 + (((((((row) & 1) << 2) | lh)) ^ (((row) >> 1) & 7)) << 3))

#define COMPUTE(cur)                                                        \
  do {                                                                      \
    bf16x8 af[4], bfr[4];                                                   \
    _Pragma("unroll")                                                       \
    for (int m = 0; m < 4; ++m)                                             \
      af[m] = *reinterpret_cast<const bf16x8*>(&As[cur][AOFF(64 * wr + 16 * m + l15)]); \
    _Pragma("unroll")                                                       \
    for (int n = 0; n < 4; ++n)                                             \
      bfr[n] = *reinterpret_cast<const bf16x8*>(&Bs[cur][AOFF(64 * wc + 16 * n + l15)]); \
    _Pragma("unroll")                                                       \
    for (int m = 0; m < 4; ++m)                                             \
      _Pragma("unroll")                                                     \
      for (int n = 0; n < 4; ++n)                                           \
        acc[m][n] = __builtin_amdgcn_mfma_f32_16x16x32_bf16(af[m], bfr[n], acc[m][n], 0, 0, 0); \
  } while (0)

#define WAITV(N) asm volatile("s_waitcnt vmcnt(" #N ")" ::: "memory")
#define BAR()    asm volatile("s_barrier" ::: "memory")

  STAGE(0, 0);
  STAGE(1, 1);
#pragma unroll
  for (int t = 0; t < 14; ++t) {
    WAITV(3);                       // tile t's 3 loads done; t+1's in flight
    BAR();
    STAGE((t + 2) % 3, t + 2);      // overwrites buf consumed at iter t-1
    COMPUTE(t % 3);
  }
  WAITV(3); BAR(); COMPUTE(2);      // t=14 (tile 15's loads still in flight)
  WAITV(0); BAR(); COMPUTE(0);      // t=15
#undef STAGE
#undef COMPUTE
#undef WAITV
#undef BAR

  // ---- epilogue: a = sigmoid(-gate), v = sigmoid(gate)*g(hidden); av packed;
  // ---- fused scan pass1: per 32-row chunk, (A,B) = chunk-composed affine map.
  const int row_w = m_base + 64 * wr;
#pragma unroll
  for (int h = 0; h < 2; ++h) {          // chunk half: rows [32h, 32h+32) of wave
    float Ar[2][2], Br[2][2];            // [n][mm]
#pragma unroll
    for (int mm = 0; mm < 2; ++mm) {
      const int m = 2 * h + mm;
#pragma unroll
      for (int n = 0; n < 2; ++n) {
        float A = 1.f, Bv = 0.f;
        const int dch = d0 + 32 * wc + 16 * n + l15;
#pragma unroll
        for (int r = 0; r < 4; ++r) {
          float hid = acc[m][n][r];
          float gt  = acc[m][n + 2][r];
          float e   = __expf(gt);
          float inv = 1.f / (1.f + e);         // a = sigmoid(-gate)
          float g   = (hid >= 0.f) ? (hid + 0.5f) : (1.f / (1.f + __expf(-hid)));
          float v   = (e * inv) * g;           // z * g
          u16 abf = f2bf(inv);
          u16 vbf = f2bf(v);
          const int grow = row_w + 16 * m + 4 * lh + r;
          av_buf[(size_t)grow * D_DIM + dch] = (u32)abf | ((u32)vbf << 16);
          float afv = bf2f(abf), vfv = bf2f(vbf);
          Bv = afv * Bv + vfv;
          A *= afv;
        }
        Ar[n][mm] = A; Br[n][mm] = Bv;
      }
    }
    // inclusive scan across lh (4 segments of 4 rows each), per (n, mm)
#pragma unroll
    for (int n = 0; n < 2; ++n)
#pragma unroll
      for (int mm = 0; mm < 2; ++mm) {
        float A = Ar[n][mm], Bv = Br[n][mm];
#pragma unroll
        for (int d = 1; d <= 2; d <<= 1) {
          float pA = __shfl(A, lane - 16 * d);
          float pB = __shfl(Bv, lane - 16 * d);
          if (lh >= d) { Bv = A * pB + Bv; A = A * pA; }
        }
        Ar[n][mm] = A; Br[n][mm] = Bv;
      }
    if (lh == 3) {   // lanes 48..63 hold full 16-row segment results
      const int grow = row_w + 32 * h;
      const int b = grow >> 13;           // / 8192
      const int c = (grow & 8191) >> 5;   // / 32
      const size_t o = ((size_t)(b * NC + c)) * D_DIM;
#pragma unroll
      for (int n = 0; n < 2; ++n) {
        const int dch = d0 + 32 * wc + 16 * n + l15;
        float Ac = Ar[n][0] * Ar[n][1];
        float Bc = Ar[n][1] * Br[n][0] + Br[n][1];
        Asum[o + dch] = Ac;
        Bsum[o + dch] = Bc;
      }
    }
  }
}

// ------- chunk-level scan: one wave per (b,d) channel, shfl affine scan -------

__global__ __launch_bounds__(256) void scan_pass2(const float* __restrict__ Asum,
                                                  const float* __restrict__ Bsum,
                                                  float* __restrict__ carry) {
  const int w    = (blockIdx.x << 2) + (threadIdx.x >> 6);  // 0..2047
  const int lane = threadIdx.x & 63;
  const int b = w >> 9;
  const int d = w & 511;
  const size_t base = ((size_t)(b * NC + lane * 4)) * D_DIM + d;
  float A[4], Bv[4];
#pragma unroll
  for (int i = 0; i < 4; ++i) {
    A[i]  = Asum[base + (size_t)i * D_DIM];
    Bv[i] = Bsum[base + (size_t)i * D_DIM];
  }
  float La = 1.f, Lb = 0.f;
#pragma unroll
  for (int i = 0; i < 4; ++i) { Lb = A[i] * Lb + Bv[i]; La *= A[i]; }
  float Sa = La, Sb = Lb;
#pragma unroll
  for (int dlt = 1; dlt < 64; dlt <<= 1) {
    float pa = __shfl_up(Sa, dlt, 64);
    float pb = __shfl_up(Sb, dlt, 64);
    if (lane >= dlt) { Sb = Sa * pb + Sb; Sa = Sa * pa; }
  }
  float Eb = __shfl_up(Sb, 1, 64);
  float h = (lane == 0) ? 0.f : Eb;
#pragma unroll
  for (int i = 0; i < 4; ++i) {
    carry[base + (size_t)i * D_DIM] = h;
    h = A[i] * h + Bv[i];
  }
}

// ---------------- final within-chunk scan + output (d2, 16 waves/CU) ---------

__global__ __launch_bounds__(256) void scan_pass3(const u32* __restrict__ av_buf,
                                                  const float2* __restrict__ carry,
                                                  float2* __restrict__ out) {
  const int c  = blockIdx.x;
  const int b  = blockIdx.y;
  const int d2 = threadIdx.x;       // 0..255 (channel pair)
  float2 hh = carry[((size_t)(b * NC + c)) * 256 + d2];
  float h0 = hh.x, h1 = hh.y;
  const size_t rowbase = (size_t)b * T_DIM + (size_t)c * LCH;
  for (int t = 0; t < LCH; ++t) {
    const size_t idx = (rowbase + t) * 256 + d2;
    uint2 w = reinterpret_cast<const uint2*>(av_buf)[idx];
    h0 = bf2f(w.x & 0xffff) * h0 + bf2f(w.x >> 16);
    h1 = bf2f(w.y & 0xffff) * h1 + bf2f(w.y >> 16);
    out[idx] = make_float2(h0, h1);
  }
}

// ---------------- launch ----------------

extern "C" void kernel_launch(void* const* d_in, const int* in_sizes, int n_in,
                              void* d_out, int out_size, void* d_ws, size_t ws_size,
                              hipStream_t stream) {
  const float* x = (const float*)d_in[0];   // [4,8192,512]
  const float* W = (const float*)d_in[1];   // [512,1024]
  float* out = (float*)d_out;               // [4,8192,512]

  char* ws = (char*)d_ws;
  u16*   xb     = (u16*)(ws + 0);             // 33,554,432
  u16*   wtp    = (u16*)(ws + 33554432);      //  1,048,576
  u32*   av_buf = (u32*)(ws + 34603008);      // 67,108,864 (a lo16 | v hi16)
  float* Asum   = (float*)(ws + 101711872);   //  2,097,152
  float* Bsum   = (float*)(ws + 103809024);   //  2,097,152
  float* carry  = (float*)(ws + 105906176);   //  2,097,152  (end 108,003,328)
  if (ws_size < 108003328ULL) return;

  convert_xw<<<2304, 256, 0, stream>>>((const float4*)x, xb, W, wtp, (M_DIM * K_DIM) / 4);
  gemm_act<<<dim3(M_DIM / 256, D_DIM / 64), 512, 0, stream>>>(xb, wtp, av_buf, Asum, Bsum);
  scan_pass2<<<512, 256, 0, stream>>>(Asum, Bsum, carry);
  scan_pass3<<<dim3(NC, B_DIM), 256, 0, stream>>>(av_buf, (const float2*)carry, (float2*)out);
}